// Round 2
// baseline (206.958 us; speedup 1.0000x reference)
//
#include <hip/hip_runtime.h>
#include <cmath>

// CapsuleLayer dynamic routing, B=64, Ni=2048, Di=16, No=32, Do=16 (fp32).
// R2: single fused kernel. Routing coefficients c2[b][n][o] depend only on
// hsum = sum_d uhat (local per (b,n)), computed inline from the LDS-staged W
// tile -> W read exactly once, no c2 global round-trip. Partial sums go to
// b-major scratch; a small reduce kernel finishes sum-over-n + squash.

#define NI 2048
#define NG 8           // n's per block -> 256 blocks of 1024 threads
#define WLS 516        // Wl row stride (pad: 516%32=4 -> <=2-way on staging)
#define XLS 66

__global__ __launch_bounds__(1024) void caps_fused_kernel(
    const float* __restrict__ x, const float* __restrict__ W,
    float* __restrict__ partial)
{
  const int gidx = blockIdx.x;   // n-group 0..255
  const int t = threadIdx.x;     // 0..1023
  const int g  = t & 63;
  const int wv = t >> 6;         // wave 0..15
  const int hh = wv >> 3;        // o-half handled by this wave
  const int bg = wv & 7;         // b-octet handled by this wave

  __shared__ __align__(16) float Wl[16*WLS];   // [i][cell], cell=o*16+d
  __shared__ __align__(16) float Xl[16*XLS];   // [i][b]
  __shared__ __align__(16) float WdS[32*17];   // [o][i] = sum_d W[o][d][i]
  __shared__ __align__(16) float c2s[64*32];   // [b][o]

  float sacc[8][4];
  #pragma unroll
  for (int l = 0; l < 8; ++l)
    { sacc[l][0]=0.f; sacc[l][1]=0.f; sacc[l][2]=0.f; sacc[l][3]=0.f; }

  #pragma unroll 1
  for (int nn = 0; nn < NG; ++nn) {
    const int n = gidx*NG + nn;

    // ---- stage W slab (8192 floats) transposed to i-major ----
    #pragma unroll
    for (int m2 = 0; m2 < 2; ++m2) {
      int q = t + 1024*m2;
      float4 v = *(const float4*)(W + (size_t)n*8192 + 4*q);
      int cell = q >> 2, kb = 4*(q & 3);   // flat = cell*16 + i
      Wl[(kb+0)*WLS + cell] = v.x;
      Wl[(kb+1)*WLS + cell] = v.y;
      Wl[(kb+2)*WLS + cell] = v.z;
      Wl[(kb+3)*WLS + cell] = v.w;
    }
    // ---- stage x (1024 floats) ----
    {
      int i = t & 15, b = t >> 4;
      Xl[i*XLS + b] = x[(size_t)b*(NI*16) + n*16 + i];
    }
    __syncthreads();

    // ---- Wd[o][i] = sum_d Wl[i][o*16+d] (512 threads) ----
    if (t < 512) {
      int o = t >> 4, i = t & 15;
      const float* p = &Wl[i*WLS + o*16];
      float acc = 0.f;
      #pragma unroll
      for (int d = 0; d < 16; ++d) acc += p[d];
      WdS[o*17 + i] = acc;
    }
    __syncthreads();

    // ---- hsum + 2-step routing chain -> c2s (512 threads) ----
    // thread: b = t>>3, oq = t&7 covers o = oq + 8*jj; softmax via 8-lane shuffles
    if (t < 512) {
      int b = t >> 3, oq = t & 7;
      float h[4];
      #pragma unroll
      for (int jj = 0; jj < 4; ++jj) {
        int o = oq + 8*jj;
        float acc = 0.f;
        #pragma unroll
        for (int i = 0; i < 16; ++i) acc += WdS[o*17 + i] * Xl[i*XLS + b];
        h[jj] = acc;
      }
      // b1 = h/32 ; c1 = softmax(b1) ; b2 = b1 + c1*h ; c2 = softmax(b2)
      float b1[4], e[4];
      float mx = -1e30f;
      #pragma unroll
      for (int jj = 0; jj < 4; ++jj) { b1[jj] = h[jj]*0.03125f; mx = fmaxf(mx, b1[jj]); }
      mx = fmaxf(mx, __shfl_xor(mx,1)); mx = fmaxf(mx, __shfl_xor(mx,2)); mx = fmaxf(mx, __shfl_xor(mx,4));
      float S = 0.f;
      #pragma unroll
      for (int jj = 0; jj < 4; ++jj) { e[jj] = __expf(b1[jj]-mx); S += e[jj]; }
      S += __shfl_xor(S,1); S += __shfl_xor(S,2); S += __shfl_xor(S,4);
      float inv = 1.0f/S;
      float b2[4]; float mx2 = -1e30f;
      #pragma unroll
      for (int jj = 0; jj < 4; ++jj) { b2[jj] = b1[jj] + e[jj]*inv*h[jj]; mx2 = fmaxf(mx2, b2[jj]); }
      mx2 = fmaxf(mx2, __shfl_xor(mx2,1)); mx2 = fmaxf(mx2, __shfl_xor(mx2,2)); mx2 = fmaxf(mx2, __shfl_xor(mx2,4));
      float S2 = 0.f;
      #pragma unroll
      for (int jj = 0; jj < 4; ++jj) { e[jj] = __expf(b2[jj]-mx2); S2 += e[jj]; }
      S2 += __shfl_xor(S2,1); S2 += __shfl_xor(S2,2); S2 += __shfl_xor(S2,4);
      float inv2 = 1.0f/S2;
      #pragma unroll
      for (int jj = 0; jj < 4; ++jj) c2s[b*32 + oq + 8*jj] = e[jj]*inv2;
    }
    __syncthreads();

    // ---- GEMM: thread g covers 4 consecutive cells (one d-quad, same o) ----
    float acc[8][4];
    #pragma unroll
    for (int l = 0; l < 8; ++l)
      { acc[l][0]=0.f; acc[l][1]=0.f; acc[l][2]=0.f; acc[l][3]=0.f; }

    #pragma unroll
    for (int k = 0; k < 16; ++k) {
      const float4 w4 = *(const float4*)&Wl[k*WLS + hh*256 + 4*g];
      const float4 xa = *(const float4*)&Xl[k*XLS + bg*8];
      const float4 xb = *(const float4*)&Xl[k*XLS + bg*8 + 4];
      float xv[8] = {xa.x, xa.y, xa.z, xa.w, xb.x, xb.y, xb.z, xb.w};
      #pragma unroll
      for (int l = 0; l < 8; ++l) {
        acc[l][0] += xv[l]*w4.x; acc[l][1] += xv[l]*w4.y;
        acc[l][2] += xv[l]*w4.z; acc[l][3] += xv[l]*w4.w;
      }
    }
    // weight by c2 (single o per thread) and fold into persistent sacc
    const int o = hh*16 + (g >> 2);
    #pragma unroll
    for (int l = 0; l < 8; ++l) {
      float c = c2s[(bg*8 + l)*32 + o];
      sacc[l][0] += c*acc[l][0]; sacc[l][1] += c*acc[l][1];
      sacc[l][2] += c*acc[l][2]; sacc[l][3] += c*acc[l][3];
    }
    __syncthreads();
  }

  // ---- write partial[b][gidx][cell], cell = hh*256 + 4g (b-major!) ----
  #pragma unroll
  for (int l = 0; l < 8; ++l) {
    int b = bg*8 + l;
    *(float4*)(partial + (size_t)b*(256*512) + (size_t)gidx*512 + hh*256 + 4*g)
        = make_float4(sacc[l][0], sacc[l][1], sacc[l][2], sacc[l][3]);
  }
}

// ---------------- reduce 256 group-partials + squash ----------------
__global__ __launch_bounds__(256) void caps_reduce_kernel(
    const float* __restrict__ partial, float* __restrict__ out)
{
  const int t = threadIdx.x;
  const int w4 = t >> 6, ln = t & 63;
  const int pair = blockIdx.x*4 + w4;     // (b,o), 2048 total
  const int b = pair >> 5, o = pair & 31;
  const int d = ln & 15, cg = ln >> 4;
  const float* p = partial + (size_t)b*(256*512) + o*16 + d;
  float s = 0.f;
  #pragma unroll 8
  for (int gg = cg; gg < 256; gg += 4) s += p[(size_t)gg*512];
  s += __shfl_xor(s,16); s += __shfl_xor(s,32);    // over cg
  float s2 = s*s;
  s2 += __shfl_xor(s2,1); s2 += __shfl_xor(s2,2);
  s2 += __shfl_xor(s2,4); s2 += __shfl_xor(s2,8);  // over d
  float scale = s2/(1.0f+s2)/sqrtf(s2 + 1e-7f);
  if (ln < 16) out[(size_t)b*512 + o*16 + d] = scale*s;
}

extern "C" void kernel_launch(void* const* d_in, const int* in_sizes, int n_in,
                              void* d_out, int out_size, void* d_ws, size_t ws_size,
                              hipStream_t stream) {
  const float* x = (const float*)d_in[0];   // [64,2048,16]
  const float* W = (const float*)d_in[1];   // [1,2048,32,16,16]
  if (in_sizes[0] != 64*2048*16) { const float* tmp = x; x = W; W = tmp; }
  float* out = (float*)d_out;               // [64,32,16]

  float* partial = (float*)d_ws;            // 64*256*512 f32 = 32 MB, b-major

  caps_fused_kernel<<<256, 1024, 0, stream>>>(x, W, partial);
  caps_reduce_kernel<<<512, 256, 0, stream>>>(partial, out);
}